// Round 8
// baseline (94.094 us; speedup 1.0000x reference)
//
#include <hip/hip_runtime.h>
#include <stdint.h>

#define MAX_TRIALS 50
#define MARGIN 1.0f

// K1: fused count+scan+scatter (decoupled lookback, r7-proven)
#define SBLOCK 256
#define SEG 1024                 // elements per segment (4/thread, int4)
// K2: sampler over compacted positives
#define MBLOCK 1024              // 16 waves/block
#define MME 2
#define MCHUNK (MBLOCK * MME)    // max positives per block (LDS queue bound)

#define FLAG_AGG 1ULL
#define FLAG_INC 2ULL

// ---------------- JAX threefry2x32, key = jax.random.key(42) = [0, 42] -----
// Verified bit-exact rounds 1/3/4/5/6/7 (absmax 0.0). Do not touch.
__device__ __forceinline__ uint32_t rotl32(uint32_t x, uint32_t d) {
  return (x << d) | (x >> (32u - d));
}

__device__ __forceinline__ uint32_t threefry_0_42(uint32_t x0, uint32_t x1, int which) {
  const uint32_t k0 = 0u, k1 = 42u;
  const uint32_t k2 = k0 ^ k1 ^ 0x1BD11BDAu;
  const uint32_t ks[3] = {k0, k1, k2};
  const uint32_t rotA[4] = {13u, 15u, 26u, 6u};
  const uint32_t rotB[4] = {17u, 29u, 16u, 24u};
  x0 += ks[0];
  x1 += ks[1];
#pragma unroll
  for (int r = 0; r < 5; ++r) {
#pragma unroll
    for (int j = 0; j < 4; ++j) {
      uint32_t rot = (r & 1) ? rotB[j] : rotA[j];
      x0 += x1;
      x1 = rotl32(x1, rot);
      x1 ^= x0;
    }
    x0 += ks[(r + 1) % 3];
    x1 += ks[(r + 2) % 3] + (uint32_t)(r + 1);
  }
  return which ? x1 : x0;
}

__device__ __forceinline__ float sample_u(uint32_t j, uint32_t half) {
  uint32_t x0, x1;
  int which;
  if (j < half) { x0 = j; x1 = j + half; which = 0; }
  else          { x0 = j - half; x1 = j; which = 1; }
  uint32_t bits = threefry_0_42(x0, x1, which);
  return __uint_as_float((bits >> 9) | 0x3f800000u) - 1.0f;
}

// ---------------- K1: fused count + lookback scan + DUAL compaction --------
// negScores[negRank] for negatives AND (posE,posS)[e - negRank] for positives
// -- posIdx needs no extra scan (positives before e = e - negatives before e).
// Lookback protocol byte-identical to r7 (packed flag|value, no fences;
// 1024 blocks <= co-resident capacity -> no deadlock; 0xAA poison reads as
// "not ready"). Cross-kernel visibility via kernel-boundary release/acquire
// (r1-r7 proven).
__global__ void __launch_bounds__(SBLOCK) scan_scatter_kernel(
    const float* __restrict__ scores, const int* __restrict__ labels,
    unsigned long long* __restrict__ desc, int* __restrict__ counters,
    float* __restrict__ negScores, int* __restrict__ posE,
    float* __restrict__ posS, float* __restrict__ out, int B, int nseg) {
  __shared__ int s_scan[SBLOCK];
  __shared__ int s_base;
  const int t = threadIdx.x;
  const int seg = blockIdx.x;

  if (seg == 0 && t == 0) out[0] = 0.0f;  // d_out poisoned each call; K2 accumulates

  // load my 4 consecutive elements (stable order: thread rank * 4 + k)
  int e0 = seg * SEG + 4 * t;
  int lab[4] = {1, 1, 1, 1};
  float sc[4] = {0.f, 0.f, 0.f, 0.f};
  if (e0 + 3 < B) {
    int4 L = *reinterpret_cast<const int4*>(labels + e0);
    float4 S = *reinterpret_cast<const float4*>(scores + e0);
    lab[0] = L.x; lab[1] = L.y; lab[2] = L.z; lab[3] = L.w;
    sc[0] = S.x; sc[1] = S.y; sc[2] = S.z; sc[3] = S.w;
  } else {
    for (int k = 0; k < 4; ++k) {
      int e = e0 + k;
      if (e < B) { lab[k] = labels[e]; sc[k] = scores[e]; }
    }
  }
  int c = (lab[0] == 0) + (lab[1] == 0) + (lab[2] == 0) + (lab[3] == 0);
  s_scan[t] = c;
  __syncthreads();
  for (int d = 1; d < SBLOCK; d <<= 1) {  // Hillis-Steele inclusive
    int v = (t >= d) ? s_scan[t - d] : 0;
    __syncthreads();
    s_scan[t] += v;
    __syncthreads();
  }
  const int cnt = s_scan[SBLOCK - 1];  // my segment's negative count

  if (seg == 0) {
    if (t == 0) {
      atomicExch(&desc[0], (FLAG_INC << 32) | (unsigned)cnt);
      s_base = 0;
      if (nseg == 1) counters[0] = cnt;
    }
  } else {
    if (t == 0) atomicExch(&desc[seg], (FLAG_AGG << 32) | (unsigned)cnt);
    if (t < 64) {  // wave 0: lane-parallel lookback, 64 predecessors/window
      int running = 0;
      int w = 0;
      bool done = false;
      while (!done) {
        int idx = seg - 1 - w * 64 - t;
        unsigned flag;
        int val;
        do {
          if (idx >= 0) {
            unsigned long long v = atomicAdd(&desc[idx], 0ULL);  // coherent read
            flag = (unsigned)(v >> 32);
            val = (int)(unsigned)v;
          } else {
            flag = (unsigned)FLAG_INC;
            val = 0;
          }
        } while (!__all(flag == 1u || flag == 2u));
        unsigned long long incmask = __ballot(flag == 2u);
        int contrib;
        if (incmask) {
          int l = __ffsll(incmask) - 1;      // nearest inclusive entry
          contrib = (t <= l) ? val : 0;
          done = true;
        } else {
          contrib = val;
          ++w;
        }
#pragma unroll
        for (int off = 32; off > 0; off >>= 1) contrib += __shfl_down(contrib, off, 64);
        if (t == 0) running += contrib;
      }
      if (t == 0) {
        atomicExch(&desc[seg], (FLAG_INC << 32) | (unsigned)(running + cnt));
        s_base = running;
        if (seg == nseg - 1) counters[0] = running + cnt;  // num_neg
      }
    }
  }
  __syncthreads();
  const int base = s_base;

  // dual compaction: negRank = global negatives before element e
  int negRank = base + s_scan[t] - c;
  for (int k = 0; k < 4; ++k) {
    int e = e0 + k;
    if (e < B) {
      if (lab[k] == 0) {
        negScores[negRank] = sc[k];
        ++negRank;
      } else {
        int pi = e - negRank;  // positives before e
        posE[pi] = e;
        posS[pi] = sc[k];
      }
    }
  }
}

// ---------------- K2: two-phase sampling over DENSE positives --------------
// No labels/scores reads, no wasted lanes: phase-A threefry+gathers halve vs
// r7. Partition: even chunk = ceil(np/grid) <= MCHUNK, so the proven LDS
// queue + phase B + fence-free single-atomic tail are unchanged.
__global__ void __launch_bounds__(MBLOCK, 8) warp_main(
    const int* __restrict__ posE, const float* __restrict__ posS,
    const float* __restrict__ negScores, const int* __restrict__ counters,
    float* __restrict__ out, int B) {
  __shared__ float H[MAX_TRIALS + 1];
  __shared__ int s_qe[MCHUNK];
  __shared__ float s_qs[MCHUNK];
  __shared__ int s_qn;
  __shared__ float s_bsum[MBLOCK / 64];

  const int tid = threadIdx.x;
  const int lane = tid & 63;
  const int wave = tid >> 6;

  if (tid == 0) {
    float a = 0.0f;  // fp32 sequential cumsum == jnp.cumsum of 1/k
    for (int k = 1; k <= MAX_TRIALS; ++k) { a += 1.0f / (float)k; H[k] = a; }
    s_qn = 0;
  }
  __syncthreads();

  const int num_neg = counters[0];
  if (num_neg == 0) return;        // out stays 0 (ref: valid=false)
  const int np = B - num_neg;
  if (np <= 0) return;             // out stays 0

  const float fneg = (float)num_neg;
  const uint32_t half = (uint32_t)(((unsigned long long)B * MAX_TRIALS) >> 1);

  const int nb = (int)gridDim.x;
  int chunk = (((np + nb - 1) / nb) + 1) & ~1;  // even -> 8B-aligned loads; <= MCHUNK
  const int p0 = blockIdx.x * chunk;
  const int p1 = min(p0 + chunk, np);

  float acc = 0.0f;
  int my_e[MME];
  float my_s[MME];
  int nsurv = 0;

  const int i0 = p0 + 2 * tid;
  int pe[2];
  float ps[2];
  bool val[2] = {false, false};
  if (i0 + 1 < p1) {
    int2 E = *reinterpret_cast<const int2*>(posE + i0);   // i0 even -> aligned
    float2 S = *reinterpret_cast<const float2*>(posS + i0);
    pe[0] = E.x; pe[1] = E.y;
    ps[0] = S.x; ps[1] = S.y;
    val[0] = val[1] = true;
  } else {
    for (int k = 0; k < 2; ++k) {
      if (i0 + k < p1) { pe[k] = posE[i0 + k]; ps[k] = posS[i0 + k]; val[k] = true; }
    }
  }

  // issue all 4 gathers before resolving (MLP)
  float n0[2], n1[2];
#pragma unroll
  for (int k = 0; k < 2; ++k) {
    if (val[k]) {
      uint32_t jb = (uint32_t)pe[k] * (uint32_t)MAX_TRIALS;
      float u0 = sample_u(jb, half);
      float u1 = sample_u(jb + 1u, half);
      int g0 = (int)(u0 * fneg);  // trunc toward zero == astype(int32)
      int g1 = (int)(u1 * fneg);
      if (g0 > num_neg - 1) g0 = num_neg - 1;
      if (g1 > num_neg - 1) g1 = num_neg - 1;
      n0[k] = negScores[g0];
      n1[k] = negScores[g1];
    }
  }
#pragma unroll
  for (int k = 0; k < 2; ++k) {
    if (val[k]) {
      float s = ps[k];
      if (n0[k] + MARGIN > s) {         // trials=0 -> rank=50
        float h = MARGIN - (s - n0[k]);
        if (h < 0.0f) h = 0.0f;
        acc += H[50] * h;
      } else if (n1[k] + MARGIN > s) {  // trials=1 -> rank=25
        float h = MARGIN - (s - n1[k]);
        if (h < 0.0f) h = 0.0f;
        acc += H[25] * h;
      } else {
        my_e[nsurv] = pe[k];
        my_s[nsurv] = s;
        ++nsurv;
      }
    }
  }

  // enqueue survivors (order irrelevant for the sum); LDS atomic is cheap
  int qp = 0;
  if (nsurv) qp = atomicAdd(&s_qn, nsurv);
  for (int i = 0; i < nsurv; ++i) {
    s_qe[qp + i] = my_e[i];
    s_qs[qp + i] = my_s[i];
  }
  __syncthreads();

  // phase B: one wave per survivor, lanes = trials 2..49
  const int qn = s_qn;
  for (int q = wave; q < qn; q += MBLOCK / 64) {
    float sq = s_qs[q];
    int eq = s_qe[q];
    int t = 2 + lane;
    bool viol = false;
    float neg = 0.0f;
    if (t < MAX_TRIALS) {
      float u = sample_u((uint32_t)eq * (uint32_t)MAX_TRIALS + (uint32_t)t, half);
      int idx = (int)(u * fneg);
      if (idx > num_neg - 1) idx = num_neg - 1;
      neg = negScores[idx];
      viol = (neg + MARGIN > sq);
    }
    unsigned long long vm = __ballot(viol);
    if (vm) {
      int f = __ffsll(vm) - 1;  // lowest lane == first violating trial
      if (lane == f) {
        int trials = 2 + f;
        int rank = MAX_TRIALS / (trials + 1);
        if (rank < 1) rank = 1;
        float h = MARGIN - (sq - neg);
        if (h < 0.0f) h = 0.0f;
        acc += H[rank] * h;
      }
    }
    // vm == 0 -> no violation in 50 trials -> contributes 0 (matches ref)
  }

  // block reduce -> one fence-free atomic per block (pre-scaled by 1/num_pos)
  float v = acc;
#pragma unroll
  for (int off = 32; off > 0; off >>= 1) v += __shfl_down(v, off, 64);
  if (lane == 0) s_bsum[wave] = v;
  __syncthreads();
  if (tid == 0) {
    float bs = 0.0f;
    for (int i = 0; i < MBLOCK / 64; ++i) bs += s_bsum[i];
    atomicAdd(out, bs * (1.0f / (float)np));
  }
}

extern "C" void kernel_launch(void* const* d_in, const int* in_sizes, int n_in,
                              void* d_out, int out_size, void* d_ws, size_t ws_size,
                              hipStream_t stream) {
  const float* scores = (const float*)d_in[0];
  const int* labels = (const int*)d_in[1];
  int B = in_sizes[0];
  int nseg = (B + SEG - 1) / SEG;         // 1024 for B=1M
  int nb2 = (B + MCHUNK - 1) / MCHUNK;    // 512

  // workspace layout (~12.6 MB of the 268 MB ws)
  char* ws = (char*)d_ws;
  int* counters = (int*)ws;                                   // [0]=num_neg
  unsigned long long* desc = (unsigned long long*)(ws + 64);  // nseg descriptors
  char* p = ws + 64 + 8192;                                   // 16B-aligned
  int* posE = (int*)p;                                        // B ints
  float* posS = (float*)(p + (size_t)B * 4);                  // B floats
  float* negScores = (float*)(p + (size_t)B * 8);             // B floats

  scan_scatter_kernel<<<nseg, SBLOCK, 0, stream>>>(scores, labels, desc, counters,
                                                   negScores, posE, posS,
                                                   (float*)d_out, B, nseg);
  warp_main<<<nb2, MBLOCK, 0, stream>>>(posE, posS, negScores, counters,
                                        (float*)d_out, B);
}

// Round 9
// 86.787 us; speedup vs baseline: 1.0842x; 1.0842x over previous
//
#include <hip/hip_runtime.h>
#include <stdint.h>

#define MAX_TRIALS 50
#define MARGIN 1.0f

// K1: fused count+scan+scatter (decoupled lookback) -- byte-identical to r7
#define SBLOCK 256
#define SEG 1024                 // elements per segment (4/thread, int4)
// K2: sampler
#define MBLOCK 1024              // 16 waves/block; 512 blocks -> 32 waves/CU
#define MME 2
#define MCHUNK (MBLOCK * MME)    // 2048 elements per block

#define FLAG_AGG 1ULL
#define FLAG_INC 2ULL

// ---------------- JAX threefry2x32, key = jax.random.key(42) = [0, 42] -----
// Verified bit-exact rounds 1/3/4/5/6/7/8 (absmax 0.0). Do not touch.
__device__ __forceinline__ uint32_t rotl32(uint32_t x, uint32_t d) {
  return (x << d) | (x >> (32u - d));
}

__device__ __forceinline__ uint32_t threefry_0_42(uint32_t x0, uint32_t x1, int which) {
  const uint32_t k0 = 0u, k1 = 42u;
  const uint32_t k2 = k0 ^ k1 ^ 0x1BD11BDAu;
  const uint32_t ks[3] = {k0, k1, k2};
  const uint32_t rotA[4] = {13u, 15u, 26u, 6u};
  const uint32_t rotB[4] = {17u, 29u, 16u, 24u};
  x0 += ks[0];
  x1 += ks[1];
#pragma unroll
  for (int r = 0; r < 5; ++r) {
#pragma unroll
    for (int j = 0; j < 4; ++j) {
      uint32_t rot = (r & 1) ? rotB[j] : rotA[j];
      x0 += x1;
      x1 = rotl32(x1, rot);
      x1 ^= x0;
    }
    x0 += ks[(r + 1) % 3];
    x1 += ks[(r + 2) % 3] + (uint32_t)(r + 1);
  }
  return which ? x1 : x0;
}

__device__ __forceinline__ float sample_u(uint32_t j, uint32_t half) {
  uint32_t x0, x1;
  int which;
  if (j < half) { x0 = j; x1 = j + half; which = 0; }
  else          { x0 = j - half; x1 = j; which = 1; }
  uint32_t bits = threefry_0_42(x0, x1, which);
  return __uint_as_float((bits >> 9) | 0x3f800000u) - 1.0f;
}

// ---------------- K1: fused count + decoupled-lookback scan + scatter ------
// Byte-identical to round 7 (89.5us total, absmax 0.0). Packed flag|value
// descriptors -> no fences; 1024 blocks <= co-resident capacity -> no
// deadlock; 0xAA ws poison reads as "not ready".
__global__ void __launch_bounds__(SBLOCK) scan_scatter_kernel(
    const float* __restrict__ scores, const int* __restrict__ labels,
    unsigned long long* __restrict__ desc, int* __restrict__ counters,
    float* __restrict__ negScores, float* __restrict__ out, int B, int nseg) {
  __shared__ int s_scan[SBLOCK];
  __shared__ int s_base;
  const int t = threadIdx.x;
  const int seg = blockIdx.x;

  if (seg == 0 && t == 0) out[0] = 0.0f;  // d_out poisoned each call; K2 accumulates

  int e0 = seg * SEG + 4 * t;
  int lab[4] = {1, 1, 1, 1};
  float sc[4] = {0.f, 0.f, 0.f, 0.f};
  if (e0 + 3 < B) {
    int4 L = *reinterpret_cast<const int4*>(labels + e0);
    float4 S = *reinterpret_cast<const float4*>(scores + e0);
    lab[0] = L.x; lab[1] = L.y; lab[2] = L.z; lab[3] = L.w;
    sc[0] = S.x; sc[1] = S.y; sc[2] = S.z; sc[3] = S.w;
  } else {
    for (int k = 0; k < 4; ++k) {
      int e = e0 + k;
      if (e < B) { lab[k] = labels[e]; sc[k] = scores[e]; }
    }
  }
  int c = (lab[0] == 0) + (lab[1] == 0) + (lab[2] == 0) + (lab[3] == 0);
  s_scan[t] = c;
  __syncthreads();
  for (int d = 1; d < SBLOCK; d <<= 1) {  // Hillis-Steele inclusive
    int v = (t >= d) ? s_scan[t - d] : 0;
    __syncthreads();
    s_scan[t] += v;
    __syncthreads();
  }
  const int cnt = s_scan[SBLOCK - 1];

  if (seg == 0) {
    if (t == 0) {
      atomicExch(&desc[0], (FLAG_INC << 32) | (unsigned)cnt);
      s_base = 0;
      if (nseg == 1) counters[0] = cnt;
    }
  } else {
    if (t == 0) atomicExch(&desc[seg], (FLAG_AGG << 32) | (unsigned)cnt);
    if (t < 64) {  // wave 0: lane-parallel lookback, 64 predecessors/window
      int running = 0;
      int w = 0;
      bool done = false;
      while (!done) {
        int idx = seg - 1 - w * 64 - t;
        unsigned flag;
        int val;
        do {
          if (idx >= 0) {
            unsigned long long v = atomicAdd(&desc[idx], 0ULL);  // coherent read
            flag = (unsigned)(v >> 32);
            val = (int)(unsigned)v;
          } else {
            flag = (unsigned)FLAG_INC;
            val = 0;
          }
        } while (!__all(flag == 1u || flag == 2u));
        unsigned long long incmask = __ballot(flag == 2u);
        int contrib;
        if (incmask) {
          int l = __ffsll(incmask) - 1;
          contrib = (t <= l) ? val : 0;
          done = true;
        } else {
          contrib = val;
          ++w;
        }
#pragma unroll
        for (int off = 32; off > 0; off >>= 1) contrib += __shfl_down(contrib, off, 64);
        if (t == 0) running += contrib;
      }
      if (t == 0) {
        atomicExch(&desc[seg], (FLAG_INC << 32) | (unsigned)(running + cnt));
        s_base = running;
        if (seg == nseg - 1) counters[0] = running + cnt;  // num_neg
      }
    }
  }
  __syncthreads();
  const int base = s_base;

  int pos = base + s_scan[t] - c;  // segment base + exclusive intra-segment prefix
  for (int k = 0; k < 4; ++k)
    if (lab[k] == 0) negScores[pos++] = sc[k];
}

// ---------------- K2: three-phase sampling --------------------------------
// A: 2 speculative trials/element (covers ~89% of positives).
// B: TWO survivors per wave -- lanes 0-31 = trials 2..33 of survivor q,
//    lanes 32-63 = trials 2..33 of survivor q+1; per-half ballot+ffs.
//    Halves phase-B threefry wave-inst vs r7 (the dominant VALU term).
// C: rare no-hit-by-33 survivors (~5-10% of survivors): full-wave trials
//    34..49. Same first-violation semantics as A+B+C partition trials 0..49.
// Tail: ONE fence-free atomicAdd per block (512 total, r6/r7-proven).
__global__ void __launch_bounds__(MBLOCK, 8) warp_main(
    const float* __restrict__ scores, const int* __restrict__ labels,
    const float* __restrict__ negScores, const int* __restrict__ counters,
    float* __restrict__ out, int B) {
  __shared__ float H[MAX_TRIALS + 1];
  __shared__ int s_qe[MCHUNK];
  __shared__ float s_qs[MCHUNK];
  __shared__ int s_ci[MCHUNK];  // phase-C queue (indices into s_qe/s_qs); full-size = no overflow
  __shared__ int s_qn;
  __shared__ int s_cn;
  __shared__ float s_bsum[MBLOCK / 64];

  const int tid = threadIdx.x;
  const int lane = tid & 63;
  const int wave = tid >> 6;
  const int nwaves = MBLOCK / 64;

  if (tid == 0) {
    float a = 0.0f;  // fp32 sequential cumsum == jnp.cumsum of 1/k
    for (int k = 1; k <= MAX_TRIALS; ++k) { a += 1.0f / (float)k; H[k] = a; }
    s_qn = 0;
    s_cn = 0;
  }
  __syncthreads();

  const int num_neg = counters[0];
  if (num_neg == 0) return;  // uniform exit; out[0] already 0 from K1 (ref: valid=false)

  const float fneg = (float)num_neg;
  const uint32_t half = (uint32_t)(((unsigned long long)B * MAX_TRIALS) >> 1);

  float acc = 0.0f;
  int my_e[MME];
  float my_s[MME];
  int nsurv = 0;

  // ---- phase A ----
  int e0 = blockIdx.x * MCHUNK + 2 * tid;  // lane-consecutive 8B: coalesced
  int lab[2] = {1, 1};
  float sc[2] = {0.f, 0.f};
  if (e0 + 1 < B) {
    int2 L = *reinterpret_cast<const int2*>(labels + e0);
    float2 S = *reinterpret_cast<const float2*>(scores + e0);
    lab[0] = L.x; lab[1] = L.y;
    sc[0] = S.x; sc[1] = S.y;
  } else {
    for (int k = 0; k < 2; ++k) {
      int e = e0 + k;
      if (e < B) { lab[k] = labels[e]; sc[k] = scores[e]; }
    }
  }
  float n0[2], n1[2];
#pragma unroll
  for (int k = 0; k < 2; ++k) {
    if (lab[k] == 1) {
      uint32_t jb = (uint32_t)(e0 + k) * (uint32_t)MAX_TRIALS;
      float u0 = sample_u(jb, half);
      float u1 = sample_u(jb + 1u, half);
      int g0 = (int)(u0 * fneg);  // trunc toward zero == astype(int32)
      int g1 = (int)(u1 * fneg);
      if (g0 > num_neg - 1) g0 = num_neg - 1;
      if (g1 > num_neg - 1) g1 = num_neg - 1;
      n0[k] = negScores[g0];
      n1[k] = negScores[g1];
    }
  }
#pragma unroll
  for (int k = 0; k < 2; ++k) {
    if (lab[k] == 1) {
      float s = sc[k];
      if (n0[k] + MARGIN > s) {         // trials=0 -> rank=50
        float h = MARGIN - (s - n0[k]);
        if (h < 0.0f) h = 0.0f;
        acc += H[50] * h;
      } else if (n1[k] + MARGIN > s) {  // trials=1 -> rank=25
        float h = MARGIN - (s - n1[k]);
        if (h < 0.0f) h = 0.0f;
        acc += H[25] * h;
      } else {
        my_e[nsurv] = e0 + k;
        my_s[nsurv] = s;
        ++nsurv;
      }
    }
  }

  int qp = 0;
  if (nsurv) qp = atomicAdd(&s_qn, nsurv);  // LDS atomic, cheap
  for (int i = 0; i < nsurv; ++i) {
    s_qe[qp + i] = my_e[i];
    s_qs[qp + i] = my_s[i];
  }
  __syncthreads();

  // ---- phase B: 2 survivors per wave, trials 2..33 per half-wave ----
  const int qn = s_qn;
  for (int q = wave * 2; q < qn; q += nwaves * 2) {
    int which = lane >> 5;       // 0 -> survivor q, 1 -> survivor q+1
    int qi = q + which;
    bool have = (qi < qn);
    float sq = 0.0f;
    int eq = 0;
    if (have) { sq = s_qs[qi]; eq = s_qe[qi]; }
    int t = 2 + (lane & 31);
    bool viol = false;
    float neg = 0.0f;
    if (have) {
      float u = sample_u((uint32_t)eq * (uint32_t)MAX_TRIALS + (uint32_t)t, half);
      int idx = (int)(u * fneg);
      if (idx > num_neg - 1) idx = num_neg - 1;
      neg = negScores[idx];
      viol = (neg + MARGIN > sq);
    }
    unsigned long long vm = __ballot(viol);
    unsigned myhalf = (unsigned)(vm >> (which * 32));  // my survivor's 32 trial bits
    if (have) {
      if (myhalf) {
        int f = __ffs(myhalf) - 1;  // first violating trial offset in 2..33
        if ((lane & 31) == f) {
          int trials = 2 + f;
          int rank = MAX_TRIALS / (trials + 1);  // in [1,16]
          float h = MARGIN - (sq - neg);
          if (h < 0.0f) h = 0.0f;
          acc += H[rank] * h;
        }
      } else if ((lane & 31) == 0) {
        s_ci[atomicAdd(&s_cn, 1)] = qi;  // no hit in 0..33 -> phase C
      }
    }
  }
  __syncthreads();

  // ---- phase C: full wave per hard survivor, trials 34..49 ----
  const int cn = s_cn;
  for (int c = wave; c < cn; c += nwaves) {
    int qi = s_ci[c];
    float sq = s_qs[qi];
    int eq = s_qe[qi];
    bool viol = false;
    float neg = 0.0f;
    if (lane < 16) {
      int t = 34 + lane;
      float u = sample_u((uint32_t)eq * (uint32_t)MAX_TRIALS + (uint32_t)t, half);
      int idx = (int)(u * fneg);
      if (idx > num_neg - 1) idx = num_neg - 1;
      neg = negScores[idx];
      viol = (neg + MARGIN > sq);
    }
    unsigned long long vm = __ballot(viol);
    if (vm) {
      int f = __ffsll(vm) - 1;
      if (lane == f) {
        // trials = 34+f -> trials+1 >= 35 -> rank = 50/(trials+1) = 1
        float h = MARGIN - (sq - neg);
        if (h < 0.0f) h = 0.0f;
        acc += H[1] * h;
      }
    }
    // vm == 0 -> no violation in all 50 trials -> contributes 0 (matches ref)
  }

  // ---- block reduce -> one fence-free atomic per block ----
  float v = acc;
#pragma unroll
  for (int off = 32; off > 0; off >>= 1) v += __shfl_down(v, off, 64);
  if (lane == 0) s_bsum[wave] = v;
  __syncthreads();
  if (tid == 0) {
    int np = B - num_neg;
    if (np > 0) {
      float bs = 0.0f;
      for (int i = 0; i < MBLOCK / 64; ++i) bs += s_bsum[i];
      atomicAdd(out, bs * (1.0f / (float)np));
    }
  }
}

extern "C" void kernel_launch(void* const* d_in, const int* in_sizes, int n_in,
                              void* d_out, int out_size, void* d_ws, size_t ws_size,
                              hipStream_t stream) {
  const float* scores = (const float*)d_in[0];
  const int* labels = (const int*)d_in[1];
  int B = in_sizes[0];
  int nseg = (B + SEG - 1) / SEG;         // 1024 for B=1M
  int nb2 = (B + MCHUNK - 1) / MCHUNK;    // 512

  // workspace layout (~4.2 MB, same as r7)
  char* ws = (char*)d_ws;
  int* counters = (int*)ws;                                  // [0]=num_neg
  unsigned long long* desc = (unsigned long long*)(ws + 64); // nseg packed descriptors
  float* negScores = (float*)(ws + 64 + 8 * 1024);           // B floats

  scan_scatter_kernel<<<nseg, SBLOCK, 0, stream>>>(scores, labels, desc, counters,
                                                   negScores, (float*)d_out, B, nseg);
  warp_main<<<nb2, MBLOCK, 0, stream>>>(scores, labels, negScores, counters,
                                        (float*)d_out, B);
}

// Round 10
// 85.880 us; speedup vs baseline: 1.0957x; 1.0106x over previous
//
#include <hip/hip_runtime.h>
#include <stdint.h>

#define MAX_TRIALS 50
#define MARGIN 1.0f

// K1: fused count+scan+scatter (decoupled lookback; shuffle-scan this round)
#define SBLOCK 256
#define SEG 1024                 // elements per segment (4/thread, int4)
// K2: sampler
#define MBLOCK 1024              // 16 waves/block
#define MCHUNK (MBLOCK * 2)      // elements covered per block (pair kernel: lo+hi)

#define FLAG_AGG 1ULL
#define FLAG_INC 2ULL

// ---------------- JAX threefry2x32, key = jax.random.key(42) = [0, 42] -----
// Verified bit-exact rounds 1-9 (absmax 0.0). Do not touch the rounds.
__device__ __forceinline__ uint32_t rotl32(uint32_t x, uint32_t d) {
  return (x << d) | (x >> (32u - d));
}

// Full call: BOTH outputs. For the (n,) draw with n = B*50, half = 25B:
// out0 -> element j, out1 -> element j+half. Since half = 50*(B/2),
// element e trial t pairs with element e+B/2 trial t -- one call, two elems.
__device__ __forceinline__ void threefry2_0_42(uint32_t x0, uint32_t x1,
                                               uint32_t* o0, uint32_t* o1) {
  const uint32_t k0 = 0u, k1 = 42u;
  const uint32_t k2 = k0 ^ k1 ^ 0x1BD11BDAu;
  const uint32_t ks[3] = {k0, k1, k2};
  const uint32_t rotA[4] = {13u, 15u, 26u, 6u};
  const uint32_t rotB[4] = {17u, 29u, 16u, 24u};
  x0 += ks[0];
  x1 += ks[1];
#pragma unroll
  for (int r = 0; r < 5; ++r) {
#pragma unroll
    for (int j = 0; j < 4; ++j) {
      uint32_t rot = (r & 1) ? rotB[j] : rotA[j];
      x0 += x1;
      x1 = rotl32(x1, rot);
      x1 ^= x0;
    }
    x0 += ks[(r + 1) % 3];
    x1 += ks[(r + 2) % 3] + (uint32_t)(r + 1);
  }
  *o0 = x0;
  *o1 = x1;
}

__device__ __forceinline__ float bits_to_u(uint32_t bits) {
  return __uint_as_float((bits >> 9) | 0x3f800000u) - 1.0f;  // jax uniform
}

// single-element form (phase B/C and odd-B fallback)
__device__ __forceinline__ float sample_u(uint32_t j, uint32_t half) {
  uint32_t x0, x1, o0, o1;
  int which;
  if (j < half) { x0 = j; x1 = j + half; which = 0; }
  else          { x0 = j - half; x1 = j; which = 1; }
  threefry2_0_42(x0, x1, &o0, &o1);
  return bits_to_u(which ? o1 : o0);
}

// ---------------- K1: fused count + decoupled-lookback scan + scatter ------
// r7-proven protocol (packed flag|value descriptors, no fences; 1024 blocks
// <= co-resident capacity -> no deadlock; 0xAA poison reads "not ready").
// This round: block scan via wave __shfl_up + 1 barrier (was 16 barriers).
__global__ void __launch_bounds__(SBLOCK) scan_scatter_kernel(
    const float* __restrict__ scores, const int* __restrict__ labels,
    unsigned long long* __restrict__ desc, int* __restrict__ counters,
    float* __restrict__ negScores, float* __restrict__ out, int B, int nseg) {
  __shared__ int s_wsum[4];
  __shared__ int s_base;
  const int t = threadIdx.x;
  const int lane = t & 63;
  const int wave = t >> 6;
  const int seg = blockIdx.x;

  if (seg == 0 && t == 0) out[0] = 0.0f;  // d_out poisoned each call; K2 accumulates

  int e0 = seg * SEG + 4 * t;
  int lab[4] = {1, 1, 1, 1};
  float sc[4] = {0.f, 0.f, 0.f, 0.f};
  if (e0 + 3 < B) {
    int4 L = *reinterpret_cast<const int4*>(labels + e0);
    float4 S = *reinterpret_cast<const float4*>(scores + e0);
    lab[0] = L.x; lab[1] = L.y; lab[2] = L.z; lab[3] = L.w;
    sc[0] = S.x; sc[1] = S.y; sc[2] = S.z; sc[3] = S.w;
  } else {
    for (int k = 0; k < 4; ++k) {
      int e = e0 + k;
      if (e < B) { lab[k] = labels[e]; sc[k] = scores[e]; }
    }
  }
  const int c = (lab[0] == 0) + (lab[1] == 0) + (lab[2] == 0) + (lab[3] == 0);

  // wave-inclusive scan (registers, no barriers)
  int incl = c;
#pragma unroll
  for (int d = 1; d < 64; d <<= 1) {
    int o = __shfl_up(incl, d, 64);
    if (lane >= d) incl += o;
  }
  if (lane == 63) s_wsum[wave] = incl;
  __syncthreads();
  const int cnt = s_wsum[0] + s_wsum[1] + s_wsum[2] + s_wsum[3];
  int woff = 0;
  for (int w = 0; w < wave; ++w) woff += s_wsum[w];
  incl += woff;  // block-inclusive prefix of my 4-element count

  if (seg == 0) {
    if (t == 0) {
      atomicExch(&desc[0], (FLAG_INC << 32) | (unsigned)cnt);
      s_base = 0;
      if (nseg == 1) counters[0] = cnt;
    }
  } else {
    if (t == 0) atomicExch(&desc[seg], (FLAG_AGG << 32) | (unsigned)cnt);
    if (t < 64) {  // wave 0: lane-parallel lookback, 64 predecessors/window
      int running = 0;
      int w = 0;
      bool done = false;
      while (!done) {
        int idx = seg - 1 - w * 64 - t;
        unsigned flag;
        int val;
        do {
          if (idx >= 0) {
            unsigned long long v = atomicAdd(&desc[idx], 0ULL);  // coherent read
            flag = (unsigned)(v >> 32);
            val = (int)(unsigned)v;
          } else {
            flag = (unsigned)FLAG_INC;
            val = 0;
          }
        } while (!__all(flag == 1u || flag == 2u));
        unsigned long long incmask = __ballot(flag == 2u);
        int contrib;
        if (incmask) {
          int l = __ffsll(incmask) - 1;
          contrib = (t <= l) ? val : 0;
          done = true;
        } else {
          contrib = val;
          ++w;
        }
#pragma unroll
        for (int off = 32; off > 0; off >>= 1) contrib += __shfl_down(contrib, off, 64);
        if (t == 0) running += contrib;
      }
      if (t == 0) {
        atomicExch(&desc[seg], (FLAG_INC << 32) | (unsigned)(running + cnt));
        s_base = running;
        if (seg == nseg - 1) counters[0] = running + cnt;  // num_neg
      }
    }
  }
  __syncthreads();
  const int base = s_base;

  int pos = base + incl - c;  // segment base + exclusive intra-segment prefix
  for (int k = 0; k < 4; ++k)
    if (lab[k] == 0) negScores[pos++] = sc[k];
}

// ---------------- K2 (even B): PAIRED three-phase sampling -----------------
// Thread handles pair (e, e+B/2): 2 threefry calls yield all 4 phase-A
// uniforms (the JAX counter pairing) -- halves phase-A RNG work vs r9.
// B: 2 survivors/wave, trials 2..33 per half-wave (r9-proven).
// C: hard survivors, trials 34..49 (r9-proven).
// Tail: ONE fence-free atomicAdd per block (r6/r7/r9-proven).
__global__ void __launch_bounds__(MBLOCK, 8) warp_main_paired(
    const float* __restrict__ scores, const int* __restrict__ labels,
    const float* __restrict__ negScores, const int* __restrict__ counters,
    float* __restrict__ out, int B) {
  __shared__ float H[MAX_TRIALS + 1];
  __shared__ int s_qe[MCHUNK];
  __shared__ float s_qs[MCHUNK];
  __shared__ int s_ci[MCHUNK];
  __shared__ int s_qn;
  __shared__ int s_cn;
  __shared__ float s_bsum[MBLOCK / 64];

  const int tid = threadIdx.x;
  const int lane = tid & 63;
  const int wave = tid >> 6;
  const int nwaves = MBLOCK / 64;

  if (tid == 0) {
    float a = 0.0f;  // fp32 sequential cumsum == jnp.cumsum of 1/k
    for (int k = 1; k <= MAX_TRIALS; ++k) { a += 1.0f / (float)k; H[k] = a; }
    s_qn = 0;
    s_cn = 0;
  }
  __syncthreads();

  const int num_neg = counters[0];
  if (num_neg == 0) return;  // uniform exit; out[0]=0 from K1 (ref: valid=false)

  const float fneg = (float)num_neg;
  const uint32_t half = (uint32_t)(((unsigned long long)B * MAX_TRIALS) >> 1);
  const int Hh = B >> 1;

  float acc = 0.0f;
  int my_e[2];
  float my_s[2];
  int nsurv = 0;

  // ---- phase A: one pair per thread ----
  const int elo = blockIdx.x * MBLOCK + tid;  // pair id in [0, B/2)
  if (elo < Hh) {
    const int ehi = elo + Hh;
    int lb[2];
    float ss[2];
    lb[0] = labels[elo]; lb[1] = labels[ehi];      // coalesced (stride-1 each)
    ss[0] = scores[elo]; ss[1] = scores[ehi];
    const uint32_t jb = (uint32_t)elo * (uint32_t)MAX_TRIALS;  // < half
    uint32_t a0, b0, a1, b1;
    threefry2_0_42(jb, jb + half, &a0, &b0);        // trial 0: lo=a0, hi=b0
    threefry2_0_42(jb + 1u, jb + 1u + half, &a1, &b1);  // trial 1
    float u0[2] = {bits_to_u(a0), bits_to_u(b0)};
    float u1[2] = {bits_to_u(a1), bits_to_u(b1)};
    const int ee[2] = {elo, ehi};
    float n0[2], n1[2];
#pragma unroll
    for (int k = 0; k < 2; ++k) {
      if (lb[k] == 1) {  // issue all 4 gathers before resolving (MLP)
        int g0 = (int)(u0[k] * fneg);  // trunc toward zero == astype(int32)
        int g1 = (int)(u1[k] * fneg);
        if (g0 > num_neg - 1) g0 = num_neg - 1;
        if (g1 > num_neg - 1) g1 = num_neg - 1;
        n0[k] = negScores[g0];
        n1[k] = negScores[g1];
      }
    }
#pragma unroll
    for (int k = 0; k < 2; ++k) {
      if (lb[k] == 1) {
        float s = ss[k];
        if (n0[k] + MARGIN > s) {         // trials=0 -> rank=50
          float h = MARGIN - (s - n0[k]);
          if (h < 0.0f) h = 0.0f;
          acc += H[50] * h;
        } else if (n1[k] + MARGIN > s) {  // trials=1 -> rank=25
          float h = MARGIN - (s - n1[k]);
          if (h < 0.0f) h = 0.0f;
          acc += H[25] * h;
        } else {
          my_e[nsurv] = ee[k];
          my_s[nsurv] = s;
          ++nsurv;
        }
      }
    }
  }

  int qp = 0;
  if (nsurv) qp = atomicAdd(&s_qn, nsurv);  // LDS atomic, cheap
  for (int i = 0; i < nsurv; ++i) {
    s_qe[qp + i] = my_e[i];
    s_qs[qp + i] = my_s[i];
  }
  __syncthreads();

  // ---- phase B: 2 survivors per wave, trials 2..33 per half-wave ----
  const int qn = s_qn;
  for (int q = wave * 2; q < qn; q += nwaves * 2) {
    int which = lane >> 5;  // 0 -> survivor q, 1 -> survivor q+1
    int qi = q + which;
    bool have = (qi < qn);
    float sq = 0.0f;
    int eq = 0;
    if (have) { sq = s_qs[qi]; eq = s_qe[qi]; }
    int t = 2 + (lane & 31);
    bool viol = false;
    float neg = 0.0f;
    if (have) {
      float u = sample_u((uint32_t)eq * (uint32_t)MAX_TRIALS + (uint32_t)t, half);
      int idx = (int)(u * fneg);
      if (idx > num_neg - 1) idx = num_neg - 1;
      neg = negScores[idx];
      viol = (neg + MARGIN > sq);
    }
    unsigned long long vm = __ballot(viol);
    unsigned myhalf = (unsigned)(vm >> (which * 32));
    if (have) {
      if (myhalf) {
        int f = __ffs(myhalf) - 1;  // first violating trial offset (2..33)
        if ((lane & 31) == f) {
          int trials = 2 + f;
          int rank = MAX_TRIALS / (trials + 1);  // in [1,16]
          float h = MARGIN - (sq - neg);
          if (h < 0.0f) h = 0.0f;
          acc += H[rank] * h;
        }
      } else if ((lane & 31) == 0) {
        s_ci[atomicAdd(&s_cn, 1)] = qi;  // no hit in 0..33 -> phase C
      }
    }
  }
  __syncthreads();

  // ---- phase C: full wave per hard survivor, trials 34..49 ----
  const int cn = s_cn;
  for (int c = wave; c < cn; c += nwaves) {
    int qi = s_ci[c];
    float sq = s_qs[qi];
    int eq = s_qe[qi];
    bool viol = false;
    float neg = 0.0f;
    if (lane < 16) {
      int t = 34 + lane;
      float u = sample_u((uint32_t)eq * (uint32_t)MAX_TRIALS + (uint32_t)t, half);
      int idx = (int)(u * fneg);
      if (idx > num_neg - 1) idx = num_neg - 1;
      neg = negScores[idx];
      viol = (neg + MARGIN > sq);
    }
    unsigned long long vm = __ballot(viol);
    if (vm) {
      int f = __ffsll(vm) - 1;
      if (lane == f) {
        // trials >= 34 -> rank = 50/(trials+1) = 1
        float h = MARGIN - (sq - neg);
        if (h < 0.0f) h = 0.0f;
        acc += H[1] * h;
      }
    }
  }

  // ---- block reduce -> one fence-free atomic per block ----
  float v = acc;
#pragma unroll
  for (int off = 32; off > 0; off >>= 1) v += __shfl_down(v, off, 64);
  if (lane == 0) s_bsum[wave] = v;
  __syncthreads();
  if (tid == 0) {
    int np = B - num_neg;
    if (np > 0) {
      float bs = 0.0f;
      for (int i = 0; i < MBLOCK / 64; ++i) bs += s_bsum[i];
      atomicAdd(out, bs * (1.0f / (float)np));
    }
  }
}

// ---------------- K2 fallback (odd B): r9 kernel verbatim ------------------
__global__ void __launch_bounds__(MBLOCK, 8) warp_main_generic(
    const float* __restrict__ scores, const int* __restrict__ labels,
    const float* __restrict__ negScores, const int* __restrict__ counters,
    float* __restrict__ out, int B) {
  __shared__ float H[MAX_TRIALS + 1];
  __shared__ int s_qe[MCHUNK];
  __shared__ float s_qs[MCHUNK];
  __shared__ int s_ci[MCHUNK];
  __shared__ int s_qn;
  __shared__ int s_cn;
  __shared__ float s_bsum[MBLOCK / 64];

  const int tid = threadIdx.x;
  const int lane = tid & 63;
  const int wave = tid >> 6;
  const int nwaves = MBLOCK / 64;

  if (tid == 0) {
    float a = 0.0f;
    for (int k = 1; k <= MAX_TRIALS; ++k) { a += 1.0f / (float)k; H[k] = a; }
    s_qn = 0;
    s_cn = 0;
  }
  __syncthreads();

  const int num_neg = counters[0];
  if (num_neg == 0) return;

  const float fneg = (float)num_neg;
  const uint32_t half = (uint32_t)(((unsigned long long)B * MAX_TRIALS) >> 1);

  float acc = 0.0f;
  int my_e[2];
  float my_s[2];
  int nsurv = 0;

  int e0 = blockIdx.x * MCHUNK + 2 * tid;
  int lab[2] = {1, 1};
  float sc[2] = {0.f, 0.f};
  if (e0 + 1 < B) {
    int2 L = *reinterpret_cast<const int2*>(labels + e0);
    float2 S = *reinterpret_cast<const float2*>(scores + e0);
    lab[0] = L.x; lab[1] = L.y;
    sc[0] = S.x; sc[1] = S.y;
  } else {
    for (int k = 0; k < 2; ++k) {
      int e = e0 + k;
      if (e < B) { lab[k] = labels[e]; sc[k] = scores[e]; }
    }
  }
  float n0[2], n1[2];
#pragma unroll
  for (int k = 0; k < 2; ++k) {
    if (lab[k] == 1) {
      uint32_t jb = (uint32_t)(e0 + k) * (uint32_t)MAX_TRIALS;
      float u0 = sample_u(jb, half);
      float u1 = sample_u(jb + 1u, half);
      int g0 = (int)(u0 * fneg);
      int g1 = (int)(u1 * fneg);
      if (g0 > num_neg - 1) g0 = num_neg - 1;
      if (g1 > num_neg - 1) g1 = num_neg - 1;
      n0[k] = negScores[g0];
      n1[k] = negScores[g1];
    }
  }
#pragma unroll
  for (int k = 0; k < 2; ++k) {
    if (lab[k] == 1) {
      float s = sc[k];
      if (n0[k] + MARGIN > s) {
        float h = MARGIN - (s - n0[k]);
        if (h < 0.0f) h = 0.0f;
        acc += H[50] * h;
      } else if (n1[k] + MARGIN > s) {
        float h = MARGIN - (s - n1[k]);
        if (h < 0.0f) h = 0.0f;
        acc += H[25] * h;
      } else {
        my_e[nsurv] = e0 + k;
        my_s[nsurv] = s;
        ++nsurv;
      }
    }
  }

  int qp = 0;
  if (nsurv) qp = atomicAdd(&s_qn, nsurv);
  for (int i = 0; i < nsurv; ++i) {
    s_qe[qp + i] = my_e[i];
    s_qs[qp + i] = my_s[i];
  }
  __syncthreads();

  const int qn = s_qn;
  for (int q = wave * 2; q < qn; q += nwaves * 2) {
    int which = lane >> 5;
    int qi = q + which;
    bool have = (qi < qn);
    float sq = 0.0f;
    int eq = 0;
    if (have) { sq = s_qs[qi]; eq = s_qe[qi]; }
    int t = 2 + (lane & 31);
    bool viol = false;
    float neg = 0.0f;
    if (have) {
      float u = sample_u((uint32_t)eq * (uint32_t)MAX_TRIALS + (uint32_t)t, half);
      int idx = (int)(u * fneg);
      if (idx > num_neg - 1) idx = num_neg - 1;
      neg = negScores[idx];
      viol = (neg + MARGIN > sq);
    }
    unsigned long long vm = __ballot(viol);
    unsigned myhalf = (unsigned)(vm >> (which * 32));
    if (have) {
      if (myhalf) {
        int f = __ffs(myhalf) - 1;
        if ((lane & 31) == f) {
          int trials = 2 + f;
          int rank = MAX_TRIALS / (trials + 1);
          float h = MARGIN - (sq - neg);
          if (h < 0.0f) h = 0.0f;
          acc += H[rank] * h;
        }
      } else if ((lane & 31) == 0) {
        s_ci[atomicAdd(&s_cn, 1)] = qi;
      }
    }
  }
  __syncthreads();

  const int cn = s_cn;
  for (int c = wave; c < cn; c += nwaves) {
    int qi = s_ci[c];
    float sq = s_qs[qi];
    int eq = s_qe[qi];
    bool viol = false;
    float neg = 0.0f;
    if (lane < 16) {
      int t = 34 + lane;
      float u = sample_u((uint32_t)eq * (uint32_t)MAX_TRIALS + (uint32_t)t, half);
      int idx = (int)(u * fneg);
      if (idx > num_neg - 1) idx = num_neg - 1;
      neg = negScores[idx];
      viol = (neg + MARGIN > sq);
    }
    unsigned long long vm = __ballot(viol);
    if (vm) {
      int f = __ffsll(vm) - 1;
      if (lane == f) {
        float h = MARGIN - (sq - neg);
        if (h < 0.0f) h = 0.0f;
        acc += H[1] * h;
      }
    }
  }

  float v = acc;
#pragma unroll
  for (int off = 32; off > 0; off >>= 1) v += __shfl_down(v, off, 64);
  if (lane == 0) s_bsum[wave] = v;
  __syncthreads();
  if (tid == 0) {
    int np = B - num_neg;
    if (np > 0) {
      float bs = 0.0f;
      for (int i = 0; i < MBLOCK / 64; ++i) bs += s_bsum[i];
      atomicAdd(out, bs * (1.0f / (float)np));
    }
  }
}

extern "C" void kernel_launch(void* const* d_in, const int* in_sizes, int n_in,
                              void* d_out, int out_size, void* d_ws, size_t ws_size,
                              hipStream_t stream) {
  const float* scores = (const float*)d_in[0];
  const int* labels = (const int*)d_in[1];
  int B = in_sizes[0];
  int nseg = (B + SEG - 1) / SEG;  // 1024 for B=1M

  // workspace layout (~4.2 MB, same as r7/r9)
  char* ws = (char*)d_ws;
  int* counters = (int*)ws;                                  // [0]=num_neg
  unsigned long long* desc = (unsigned long long*)(ws + 64); // nseg packed descriptors
  float* negScores = (float*)(ws + 64 + 8 * 1024);           // B floats

  scan_scatter_kernel<<<nseg, SBLOCK, 0, stream>>>(scores, labels, desc, counters,
                                                   negScores, (float*)d_out, B, nseg);
  if ((B & 1) == 0) {
    int nbp = ((B >> 1) + MBLOCK - 1) / MBLOCK;  // 512 for B=1M
    warp_main_paired<<<nbp, MBLOCK, 0, stream>>>(scores, labels, negScores, counters,
                                                 (float*)d_out, B);
  } else {
    int nbg = (B + MCHUNK - 1) / MCHUNK;
    warp_main_generic<<<nbg, MBLOCK, 0, stream>>>(scores, labels, negScores, counters,
                                                  (float*)d_out, B);
  }
}